// Round 11
// baseline (83.612 us; speedup 1.0000x reference)
//
#include <hip/hip_runtime.h>
#include <stdint.h>

// Problem constants
#define BB   512
#define KNB  36
#define DD   1024
#define MM   (BB*KNB)   // 18432 rows
#define NN   1024       // out dim

typedef float  f32x4  __attribute__((ext_vector_type(4)));
typedef __bf16 bf16x8 __attribute__((ext_vector_type(8)));
typedef unsigned short u16;
typedef unsigned int   u32;

// ---------- helpers ----------
__device__ __forceinline__ u16 f2bf(float f) {
    u32 u = __float_as_uint(f);
    u32 r = (u + 0x7fffu + ((u >> 16) & 1u)) >> 16;   // RNE
    return (u16)r;
}

__device__ __forceinline__ void gld16(const void* g, void* l) {
    __builtin_amdgcn_global_load_lds(
        (const __attribute__((address_space(1))) u32*)g,
        (__attribute__((address_space(3))) u32*)l,
        16, 0, 0);
}

__device__ __forceinline__ bf16x8 cvt8(f32x4 lo, f32x4 hi) {
    bf16x8 r;
    r[0] = (__bf16)lo.x; r[1] = (__bf16)lo.y; r[2] = (__bf16)lo.z; r[3] = (__bf16)lo.w;
    r[4] = (__bf16)hi.x; r[5] = (__bf16)hi.y; r[6] = (__bf16)hi.z; r[7] = (__bf16)hi.w;
    return r;
}

// cast 8 f32 -> 8 bf16, source chunk XOR-permuted within the 64-col tile
__device__ __forceinline__ void cast_chunk_swz(const float* __restrict__ in,
                                               u16* __restrict__ out,
                                               long long c, int r) {
    long long src = (c & ~7LL) | ((c & 7) ^ (r & 7));
    const f32x4* p = (const f32x4*)(in + src * 8);
    f32x4 v0 = p[0], v1 = p[1];
    union { u16 us[8]; uint4 u4; } pk;
    pk.us[0] = f2bf(v0.x); pk.us[1] = f2bf(v0.y);
    pk.us[2] = f2bf(v0.z); pk.us[3] = f2bf(v0.w);
    pk.us[4] = f2bf(v1.x); pk.us[5] = f2bf(v1.y);
    pk.us[6] = f2bf(v1.z); pk.us[7] = f2bf(v1.w);
    *((uint4*)(out + c * 8)) = pk.u4;
}

// ---------- kernel 1: prep (small) ----------
// blocks [0,72):     gaussian-mixture ws (summed over neighbours) -> wsT[4][MM]
// blocks [72,584):   W f32->bf16 cast, pre-swizzled (1024 rows x 128 chunks)
#define WS_BLOCKS   72
#define CW_BLOCKS   512
__global__ void prep_kernel(const float* __restrict__ rrw,
                            const float* __restrict__ mean,
                            const float* __restrict__ prec,
                            float* __restrict__ wsT,
                            const float* __restrict__ W,
                            u16* __restrict__ Wbf) {
    const int blk = blockIdx.x;
    if (blk < WS_BLOCKS) {
        int id = blk * 256 + threadIdx.x;
        float m0 = mean[0], m1 = mean[1], m2 = mean[2], m3 = mean[3];
        float i0 = 1.0f / (1e-14f + prec[0] * prec[0]);
        float i1 = 1.0f / (1e-14f + prec[1] * prec[1]);
        float i2 = 1.0f / (1e-14f + prec[2] * prec[2]);
        float i3 = 1.0f / (1e-14f + prec[3] * prec[3]);
        const float* p = rrw + (size_t)id * KNB;
        float a0 = 0.f, a1 = 0.f, a2 = 0.f, a3 = 0.f;
        for (int j = 0; j < KNB; ++j) {
            float x = p[j];
            float d0 = x - m0, d1 = x - m1, d2 = x - m2, d3 = x - m3;
            float e0 = expf(-0.5f * d0 * d0 * i0);
            float e1 = expf(-0.5f * d1 * d1 * i1);
            float e2 = expf(-0.5f * d2 * d2 * i2);
            float e3 = expf(-0.5f * d3 * d3 * i3);
            float inv = 1.0f / (e0 + e1 + e2 + e3);
            a0 += e0 * inv; a1 += e1 * inv; a2 += e2 * inv; a3 += e3 * inv;
        }
        wsT[0 * MM + id] = a0;
        wsT[1 * MM + id] = a1;
        wsT[2 * MM + id] = a2;
        wsT[3 * MM + id] = a3;
    } else {
        long long c = (long long)(blk - WS_BLOCKS) * 256 + threadIdx.x;  // [0,131072)
        int r = (int)(c >> 7);
        cast_chunk_swz(W, Wbf, c, r);
    }
}

// ---------- kernel 2: fused GEMM: A f32 reg-staged, counted-vmcnt dbuf -------
// ISSUE ORDER IS THE POINT (R10 bug): per half-step issue A's 8 reg-loads
// FIRST, then B's 4 gld16. vmcnt retires in issue order, so:
//   outstanding = [B(t) 4 oldest | A(t+1) 8 | B(t+1) 4 newest]
//   - s_waitcnt vmcnt(12) retires exactly B(t)  -> COMPUTE(t) safe
//   - compiler's implicit wait at WRITE_A = vmcnt(4): A regs ready,
//     B(t+1)'s 4 gld16 STAY IN FLIGHT across both barriers (T4 intact).
// R10 issued B first -> WRITE_A's wait drained B(t+1) too -> full-latency
// serialization every half-step (MfmaUtil 15, VALUBusy 9).
#define BM 128
#define BN 128
#define BK 64
#define KTILES (DD / BK)   // 16

#define VMCNT12() asm volatile("s_waitcnt vmcnt(12)" ::: "memory")
#define VMCNT0()  asm volatile("s_waitcnt vmcnt(0)" ::: "memory")
#define LGKM0()   asm volatile("s_waitcnt lgkmcnt(0)" ::: "memory")
#define BAR()     __builtin_amdgcn_s_barrier()

__global__ __launch_bounds__(256, 2) void gemm_kernel(
        const float* __restrict__ A,  // [MM][DD] f32 (raw features)
        const u16* __restrict__ Bm,   // [NN][DD] bf16, pre-swizzled
        const float* __restrict__ wsT,// [4][MM]
        float* __restrict__ out) {    // [MM][NN] f32
    __shared__ __align__(16) u16 As0[BM * BK];   // 16 KB each
    __shared__ __align__(16) u16 As1[BM * BK];
    __shared__ __align__(16) u16 Bs0[BN * BK];
    __shared__ __align__(16) u16 Bs1[BN * BK];

    const int tid = threadIdx.x;
    // XCD-bijective remap: each XCD owns 18 complete row-strips (x 8 col tiles).
    const int bid   = blockIdx.x;       // 0..1151
    const int xcd   = bid & 7;
    const int local = bid >> 3;         // 0..143
    const int by    = xcd * 18 + (local >> 3);
    const int bx    = local & 7;
    const int rowBase = by * BM;
    const int colBase = bx * BN;
    const int lane = tid & 63;
    const int w    = tid >> 6;         // wave 0..3
    const int wr   = w >> 1;           // wave row 0..1 (64-row strip)
    const int wc   = w & 1;            // wave col 0..1 (64-col strip)
    const int fr   = lane & 15;        // fragment row/col
    const int fq   = lane >> 4;        // 0..3

    f32x4 acc[4][4];
#pragma unroll
    for (int m = 0; m < 4; ++m)
#pragma unroll
        for (int n = 0; n < 4; ++n)
            acc[m][n] = (f32x4)0.0f;

    // staging geometry: per thread, rows (tid>>3)+32i, 8-elem chunk j=tid&7
    const int ar0 = tid >> 3;          // 0..31
    const int aj  = tid & 7;
    const float* abase = A + (size_t)(rowBase + ar0) * DD + aj * 8;
    const u16*   bptr  = Bm + (size_t)(colBase + ar0) * DD + aj * 8;

    f32x4 ra[4][2];

    auto ISSUE_A = [&](int kt) {       // 8 vmcnt events
#pragma unroll
        for (int i = 0; i < 4; ++i) {
            const float* src = abase + (size_t)i * 32 * DD + kt * BK;
            ra[i][0] = *(const f32x4*)src;
            ra[i][1] = *(const f32x4*)(src + 4);
        }
    };
    auto ISSUE_B = [&](u16* bs, int kt) {   // 4 vmcnt events
#pragma unroll
        for (int i = 0; i < 4; ++i)
            gld16(bptr + (size_t)i * 32 * DD + kt * BK, &bs[(i * 256 + tid) * 8]);
    };
    auto WRITE_A = [&](u16* as) {
#pragma unroll
        for (int i = 0; i < 4; ++i) {
            int r = i * 32 + ar0;
            *(bf16x8*)&as[r * BK + (aj ^ (r & 7)) * 8] = cvt8(ra[i][0], ra[i][1]);
        }
    };

    auto COMPUTE = [&](const u16* as, const u16* bs) {
#pragma unroll
        for (int kk = 0; kk < 2; ++kk) {
            bf16x8 af[4], bfv[4];
#pragma unroll
            for (int m = 0; m < 4; ++m) {
                int r = wr * 64 + m * 16 + fr;
                int g = kk * 4 + fq;               // bf16x8-chunk index
                af[m] = ((const bf16x8*)&as[r * BK])[g ^ (r & 7)];
            }
#pragma unroll
            for (int n = 0; n < 4; ++n) {
                int r = wc * 64 + n * 16 + fr;
                int g = kk * 4 + fq;
                bfv[n] = ((const bf16x8*)&bs[r * BK])[g ^ (r & 7)];
            }
#pragma unroll
            for (int m = 0; m < 4; ++m)
#pragma unroll
                for (int n = 0; n < 4; ++n)
                    acc[m][n] = __builtin_amdgcn_mfma_f32_16x16x32_bf16(
                        af[m], bfv[n], acc[m][n], 0, 0, 0);
        }
    };

    // ---- prologue: tile 0 -> buf0. A first, then B; WRITE_A's implicit wait
    // is vmcnt(4) so B(0)'s gld16 stay in flight (loop's first VMCNT12 drains them).
    ISSUE_A(0);
    ISSUE_B(Bs0, 0);
    WRITE_A(As0);
    LGKM0();
    BAR();

    // ---- steady state: 7 double-iterations; computes tiles 0..13 ----
    for (int k2 = 0; k2 < (KTILES - 2) / 2; ++k2) {
        // half-step: compute 2k2 from buf0, stage 2k2+1 into buf1
        ISSUE_A(2 * k2 + 1);
        ISSUE_B(Bs1, 2 * k2 + 1);
        VMCNT12();             // retires B(t) only; A(t+1)+B(t+1) in flight
        BAR();
        COMPUTE(As0, Bs0);     // tile 2k2
        WRITE_A(As1);          // implicit vmcnt(4): A ready, B(t+1) flying
        LGKM0();
        BAR();
        // half-step: compute 2k2+1 from buf1, stage 2k2+2 into buf0
        ISSUE_A(2 * k2 + 2);
        ISSUE_B(Bs0, 2 * k2 + 2);
        VMCNT12();
        BAR();
        COMPUTE(As1, Bs1);     // tile 2k2+1
        WRITE_A(As0);
        LGKM0();
        BAR();
    }
    // ---- tail: compute 14 (buf0), stage 15 (buf1); compute 15 ----
    ISSUE_A(KTILES - 1);
    ISSUE_B(Bs1, KTILES - 1);
    VMCNT12();                 // retires B(14)
    BAR();
    COMPUTE(As0, Bs0);         // tile 14
    WRITE_A(As1);              // vmcnt(4): A(15) ready
    LGKM0();
    VMCNT0();                  // B(15) landed
    BAR();
    COMPUTE(As1, Bs1);         // tile 15

    // epilogue: out[r][c] = acc * ws[r][kn], kn = bx>>1 (block inside one kernel slab)
    const int kn = bx >> 1;
#pragma unroll
    for (int m = 0; m < 4; ++m) {
        int r0 = rowBase + wr * 64 + m * 16 + fq * 4;
        f32x4 s = *(const f32x4*)&wsT[(size_t)kn * MM + r0];
#pragma unroll
        for (int n = 0; n < 4; ++n) {
            int c = colBase + wc * 64 + n * 16 + fr;
            float* o = out + (size_t)r0 * NN + c;
            o[0 * NN] = acc[m][n][0] * s[0];
            o[1 * NN] = acc[m][n][1] * s[1];
            o[2 * NN] = acc[m][n][2] * s[2];
            o[3 * NN] = acc[m][n][3] * s[3];
        }
    }
}

// ---------- launch ----------
extern "C" void kernel_launch(void* const* d_in, const int* in_sizes, int n_in,
                              void* d_out, int out_size, void* d_ws, size_t ws_size,
                              hipStream_t stream) {
    const float* feat = (const float*)d_in[0];   // [512][36][1024]
    const float* rrw  = (const float*)d_in[1];   // [512][36][36]
    const float* mean = (const float*)d_in[2];   // [4]
    const float* prec = (const float*)d_in[3];   // [4]
    const float* W    = (const float*)d_in[4];   // [4][256][1024] == [1024][1024]
    float* out = (float*)d_out;

    // workspace layout
    char* ws = (char*)d_ws;
    float* wsT = (float*)ws;                          // 294,912 B
    u16*   Wbf = (u16*)(ws + 294912);                 // 2,097,152 B

    prep_kernel<<<dim3(WS_BLOCKS + CW_BLOCKS), dim3(256), 0, stream>>>(
        rrw, mean, prec, wsT, W, Wbf);
    gemm_kernel<<<dim3((MM / BM) * (NN / BN)), dim3(256), 0, stream>>>(feat, Wbf, wsT, out);
}

// Round 12
// 81.319 us; speedup vs baseline: 1.0282x; 1.0282x over previous
//
#include <hip/hip_runtime.h>
#include <stdint.h>

// Problem constants
#define BB   512
#define KNB  36
#define DD   1024
#define MM   (BB*KNB)   // 18432 rows
#define NN   1024       // out dim

typedef float  f32x4  __attribute__((ext_vector_type(4)));
typedef __bf16 bf16x8 __attribute__((ext_vector_type(8)));
typedef unsigned short u16;
typedef unsigned int   u32;

// ---------- helpers ----------
__device__ __forceinline__ u16 f2bf(float f) {
    u32 u = __float_as_uint(f);
    u32 r = (u + 0x7fffu + ((u >> 16) & 1u)) >> 16;   // RNE
    return (u16)r;
}

__device__ __forceinline__ void gld16(const void* g, void* l) {
    __builtin_amdgcn_global_load_lds(
        (const __attribute__((address_space(1))) u32*)g,
        (__attribute__((address_space(3))) u32*)l,
        16, 0, 0);
}

__device__ __forceinline__ bf16x8 cvt8(f32x4 lo, f32x4 hi) {
    bf16x8 r;
    r[0] = (__bf16)lo.x; r[1] = (__bf16)lo.y; r[2] = (__bf16)lo.z; r[3] = (__bf16)lo.w;
    r[4] = (__bf16)hi.x; r[5] = (__bf16)hi.y; r[6] = (__bf16)hi.z; r[7] = (__bf16)hi.w;
    return r;
}

// cast 8 f32 -> 8 bf16, source chunk XOR-permuted within the 64-col tile
__device__ __forceinline__ void cast_chunk_swz(const float* __restrict__ in,
                                               u16* __restrict__ out,
                                               long long c, int r) {
    long long src = (c & ~7LL) | ((c & 7) ^ (r & 7));
    const f32x4* p = (const f32x4*)(in + src * 8);
    f32x4 v0 = p[0], v1 = p[1];
    union { u16 us[8]; uint4 u4; } pk;
    pk.us[0] = f2bf(v0.x); pk.us[1] = f2bf(v0.y);
    pk.us[2] = f2bf(v0.z); pk.us[3] = f2bf(v0.w);
    pk.us[4] = f2bf(v1.x); pk.us[5] = f2bf(v1.y);
    pk.us[6] = f2bf(v1.z); pk.us[7] = f2bf(v1.w);
    *((uint4*)(out + c * 8)) = pk.u4;
}

// ---------- kernel 1: prep (ws + W-cast only; A-cast is fused into the GEMM) --
#define WS_BLOCKS   72
#define CW_BLOCKS   512
__global__ void prep_kernel(const float* __restrict__ rrw,
                            const float* __restrict__ mean,
                            const float* __restrict__ prec,
                            float* __restrict__ wsT,
                            const float* __restrict__ W,
                            u16* __restrict__ Wbf) {
    const int blk = blockIdx.x;
    if (blk < WS_BLOCKS) {
        int id = blk * 256 + threadIdx.x;
        float m0 = mean[0], m1 = mean[1], m2 = mean[2], m3 = mean[3];
        float i0 = 1.0f / (1e-14f + prec[0] * prec[0]);
        float i1 = 1.0f / (1e-14f + prec[1] * prec[1]);
        float i2 = 1.0f / (1e-14f + prec[2] * prec[2]);
        float i3 = 1.0f / (1e-14f + prec[3] * prec[3]);
        const float* p = rrw + (size_t)id * KNB;
        float a0 = 0.f, a1 = 0.f, a2 = 0.f, a3 = 0.f;
        for (int j = 0; j < KNB; ++j) {
            float x = p[j];
            float d0 = x - m0, d1 = x - m1, d2 = x - m2, d3 = x - m3;
            float e0 = expf(-0.5f * d0 * d0 * i0);
            float e1 = expf(-0.5f * d1 * d1 * i1);
            float e2 = expf(-0.5f * d2 * d2 * i2);
            float e3 = expf(-0.5f * d3 * d3 * i3);
            float inv = 1.0f / (e0 + e1 + e2 + e3);
            a0 += e0 * inv; a1 += e1 * inv; a2 += e2 * inv; a3 += e3 * inv;
        }
        wsT[0 * MM + id] = a0;
        wsT[1 * MM + id] = a1;
        wsT[2 * MM + id] = a2;
        wsT[3 * MM + id] = a3;
    } else {
        long long c = (long long)(blk - WS_BLOCKS) * 256 + threadIdx.x;  // [0,131072)
        int r = (int)(c >> 7);
        cast_chunk_swz(W, Wbf, c, r);
    }
}

// ---------- kernel 2: fused GEMM, single-buffer, ONE drain per K-step --------
// R6's barrier structure (one cold-latency window per K-step) with the A-cast
// fused inside the window:
//   BAR -> ISSUE_A (8 dwordx4 to regs) -> ISSUE_B (4 gld16)
//       -> WRITE_A (compiler waits vmcnt(4): A ready, B STILL FLYING;
//          cvt+ds_write run under B's latency shadow)
//       -> __syncthreads (drains B once) -> COMPUTE.
// Lessons encoded: no barrier between issue and WRITE_A (R4's two-latency
// bug); no cross-barrier counted vmcnt with reg-staged loads (R10/R11: the
// scheduler sinks plain loads toward their use, breaking hand-set counts).
#define BM 128
#define BN 128
#define BK 64
#define KTILES (DD / BK)   // 16

__global__ __launch_bounds__(256, 3) void gemm_kernel(
        const float* __restrict__ A,  // [MM][DD] f32 (raw features)
        const u16* __restrict__ Bm,   // [NN][DD] bf16, pre-swizzled
        const float* __restrict__ wsT,// [4][MM]
        float* __restrict__ out) {    // [MM][NN] f32
    __shared__ __align__(16) u16 As[BM * BK];   // 16 KB
    __shared__ __align__(16) u16 Bs[BN * BK];   // 16 KB

    const int tid = threadIdx.x;
    // XCD-bijective remap: each XCD owns 18 complete row-strips (x 8 col tiles).
    const int bid   = blockIdx.x;       // 0..1151
    const int xcd   = bid & 7;
    const int local = bid >> 3;         // 0..143
    const int by    = xcd * 18 + (local >> 3);
    const int bx    = local & 7;
    const int rowBase = by * BM;
    const int colBase = bx * BN;
    const int lane = tid & 63;
    const int w    = tid >> 6;         // wave 0..3
    const int wr   = w >> 1;           // wave row 0..1 (64-row strip)
    const int wc   = w & 1;            // wave col 0..1 (64-col strip)
    const int fr   = lane & 15;        // fragment row/col
    const int fq   = lane >> 4;        // 0..3

    f32x4 acc[4][4];
#pragma unroll
    for (int m = 0; m < 4; ++m)
#pragma unroll
        for (int n = 0; n < 4; ++n)
            acc[m][n] = (f32x4)0.0f;

    // staging geometry: per thread, rows (tid>>3)+32i, 8-elem chunk j=tid&7
    const int ar0 = tid >> 3;          // 0..31
    const int aj  = tid & 7;
    const float* abase = A + (size_t)(rowBase + ar0) * DD + aj * 8;
    const u16*   bptr  = Bm + (size_t)(colBase + ar0) * DD + aj * 8;

    f32x4 ra[4][2];

    auto ISSUE_A = [&](int kt) {       // 8 plain dwordx4 loads -> regs
#pragma unroll
        for (int i = 0; i < 4; ++i) {
            const float* src = abase + (size_t)i * 32 * DD + kt * BK;
            ra[i][0] = *(const f32x4*)src;
            ra[i][1] = *(const f32x4*)(src + 4);
        }
    };
    auto ISSUE_B = [&](int kt) {       // 4 gld16 (issued after A: stays newest)
#pragma unroll
        for (int i = 0; i < 4; ++i)
            gld16(bptr + (size_t)i * 32 * DD + kt * BK, &Bs[(i * 256 + tid) * 8]);
    };
    auto WRITE_A = [&]() {             // cvt once + swizzled ds_write
#pragma unroll
        for (int i = 0; i < 4; ++i) {
            int r = i * 32 + ar0;
            *(bf16x8*)&As[r * BK + (aj ^ (r & 7)) * 8] = cvt8(ra[i][0], ra[i][1]);
        }
    };

    auto COMPUTE = [&]() {
#pragma unroll
        for (int kk = 0; kk < 2; ++kk) {
            bf16x8 af[4], bfv[4];
#pragma unroll
            for (int m = 0; m < 4; ++m) {
                int r = wr * 64 + m * 16 + fr;
                int g = kk * 4 + fq;               // bf16x8-chunk index
                af[m] = ((const bf16x8*)&As[r * BK])[g ^ (r & 7)];
            }
#pragma unroll
            for (int n = 0; n < 4; ++n) {
                int r = wc * 64 + n * 16 + fr;
                int g = kk * 4 + fq;
                bfv[n] = ((const bf16x8*)&Bs[r * BK])[g ^ (r & 7)];
            }
#pragma unroll
            for (int m = 0; m < 4; ++m)
#pragma unroll
                for (int n = 0; n < 4; ++n)
                    acc[m][n] = __builtin_amdgcn_mfma_f32_16x16x32_bf16(
                        af[m], bfv[n], acc[m][n], 0, 0, 0);
        }
    };

    // ---- prologue: stage tile 0 (single window, one drain) ----
    ISSUE_A(0);
    ISSUE_B(0);
    WRITE_A();
    __syncthreads();           // drains B(0) + publishes ds_writes

    // ---- main loop ----
    for (int kt = 0; kt < KTILES; ++kt) {
        COMPUTE();             // tile kt
        if (kt + 1 < KTILES) {
            __syncthreads();   // all waves done reading As/Bs
            ISSUE_A(kt + 1);
            ISSUE_B(kt + 1);
            WRITE_A();         // waits A only (vmcnt(4)); B still flying
            __syncthreads();   // ONE drain: B's latency, cvt hidden under it
        }
    }

    // epilogue: out[r][c] = acc * ws[r][kn], kn = bx>>1 (block inside one kernel slab)
    const int kn = bx >> 1;
#pragma unroll
    for (int m = 0; m < 4; ++m) {
        int r0 = rowBase + wr * 64 + m * 16 + fq * 4;
        f32x4 s = *(const f32x4*)&wsT[(size_t)kn * MM + r0];
#pragma unroll
        for (int n = 0; n < 4; ++n) {
            int c = colBase + wc * 64 + n * 16 + fr;
            float* o = out + (size_t)r0 * NN + c;
            o[0 * NN] = acc[m][n][0] * s[0];
            o[1 * NN] = acc[m][n][1] * s[1];
            o[2 * NN] = acc[m][n][2] * s[2];
            o[3 * NN] = acc[m][n][3] * s[3];
        }
    }
}

// ---------- launch ----------
extern "C" void kernel_launch(void* const* d_in, const int* in_sizes, int n_in,
                              void* d_out, int out_size, void* d_ws, size_t ws_size,
                              hipStream_t stream) {
    const float* feat = (const float*)d_in[0];   // [512][36][1024]
    const float* rrw  = (const float*)d_in[1];   // [512][36][36]
    const float* mean = (const float*)d_in[2];   // [4]
    const float* prec = (const float*)d_in[3];   // [4]
    const float* W    = (const float*)d_in[4];   // [4][256][1024] == [1024][1024]
    float* out = (float*)d_out;

    // workspace layout
    char* ws = (char*)d_ws;
    float* wsT = (float*)ws;                          // 294,912 B
    u16*   Wbf = (u16*)(ws + 294912);                 // 2,097,152 B

    prep_kernel<<<dim3(WS_BLOCKS + CW_BLOCKS), dim3(256), 0, stream>>>(
        rrw, mean, prec, wsT, W, Wbf);
    gemm_kernel<<<dim3((MM / BM) * (NN / BN)), dim3(256), 0, stream>>>(feat, Wbf, wsT, out);
}

// Round 13
// 67.365 us; speedup vs baseline: 1.2412x; 1.2071x over previous
//
#include <hip/hip_runtime.h>
#include <stdint.h>

// Problem constants
#define BB   512
#define KNB  36
#define DD   1024
#define MM   (BB*KNB)   // 18432 rows
#define NN   1024       // out dim

typedef float  f32x4  __attribute__((ext_vector_type(4)));
typedef __bf16 bf16x8 __attribute__((ext_vector_type(8)));
typedef unsigned short u16;
typedef unsigned int   u32;

// ---------- helpers ----------
__device__ __forceinline__ u16 f2bf(float f) {
    u32 u = __float_as_uint(f);
    u32 r = (u + 0x7fffu + ((u >> 16) & 1u)) >> 16;   // RNE
    return (u16)r;
}

__device__ __forceinline__ void gld16(const void* g, void* l) {
    __builtin_amdgcn_global_load_lds(
        (const __attribute__((address_space(1))) u32*)g,
        (__attribute__((address_space(3))) u32*)l,
        16, 0, 0);
}

// cast 8 f32 -> 8 bf16, source chunk XOR-permuted within the 64-col tile
__device__ __forceinline__ void cast_chunk_swz(const float* __restrict__ in,
                                               u16* __restrict__ out,
                                               long long c, int r) {
    // c = global 8-elem chunk index (row-major, 128 chunks/row of the matrix)
    long long src = (c & ~7LL) | ((c & 7) ^ (r & 7));
    const f32x4* p = (const f32x4*)(in + src * 8);
    f32x4 v0 = p[0], v1 = p[1];
    union { u16 us[8]; uint4 u4; } pk;
    pk.us[0] = f2bf(v0.x); pk.us[1] = f2bf(v0.y);
    pk.us[2] = f2bf(v0.z); pk.us[3] = f2bf(v0.w);
    pk.us[4] = f2bf(v1.x); pk.us[5] = f2bf(v1.y);
    pk.us[6] = f2bf(v1.z); pk.us[7] = f2bf(v1.w);
    *((uint4*)(out + c * 8)) = pk.u4;
}

// ---------- kernel 1: prep ----------
// blocks [0,72):     gaussian-mixture ws -> wsT[4][MM]
// blocks [72,584):   W f32->bf16 cast, pre-swizzled
// blocks [584,1736): A f32->bf16 cast, pre-swizzled (8 chunks/thread)
#define WS_BLOCKS   72
#define CW_BLOCKS   512
#define CA_BLOCKS   1152
#define CA_THREADS  (CA_BLOCKS * 256)    // 294912; x8 chunks = 2359296 = MM*DD/8
__global__ void prep_kernel(const float* __restrict__ rrw,
                            const float* __restrict__ mean,
                            const float* __restrict__ prec,
                            float* __restrict__ wsT,
                            const float* __restrict__ W,
                            u16* __restrict__ Wbf,
                            const float* __restrict__ A,
                            u16* __restrict__ Abf) {
    const int blk = blockIdx.x;
    if (blk < WS_BLOCKS) {
        int id = blk * 256 + threadIdx.x;
        float m0 = mean[0], m1 = mean[1], m2 = mean[2], m3 = mean[3];
        float i0 = 1.0f / (1e-14f + prec[0] * prec[0]);
        float i1 = 1.0f / (1e-14f + prec[1] * prec[1]);
        float i2 = 1.0f / (1e-14f + prec[2] * prec[2]);
        float i3 = 1.0f / (1e-14f + prec[3] * prec[3]);
        const float* p = rrw + (size_t)id * KNB;
        float a0 = 0.f, a1 = 0.f, a2 = 0.f, a3 = 0.f;
        for (int j = 0; j < KNB; ++j) {
            float x = p[j];
            float d0 = x - m0, d1 = x - m1, d2 = x - m2, d3 = x - m3;
            float e0 = expf(-0.5f * d0 * d0 * i0);
            float e1 = expf(-0.5f * d1 * d1 * i1);
            float e2 = expf(-0.5f * d2 * d2 * i2);
            float e3 = expf(-0.5f * d3 * d3 * i3);
            float inv = 1.0f / (e0 + e1 + e2 + e3);
            a0 += e0 * inv; a1 += e1 * inv; a2 += e2 * inv; a3 += e3 * inv;
        }
        wsT[0 * MM + id] = a0;
        wsT[1 * MM + id] = a1;
        wsT[2 * MM + id] = a2;
        wsT[3 * MM + id] = a3;
    } else if (blk < WS_BLOCKS + CW_BLOCKS) {
        long long c = (long long)(blk - WS_BLOCKS) * 256 + threadIdx.x;  // [0,131072)
        int r = (int)(c >> 7);
        cast_chunk_swz(W, Wbf, c, r);
    } else {
        long long t = (long long)(blk - WS_BLOCKS - CW_BLOCKS) * 256 + threadIdx.x;
#pragma unroll
        for (int k = 0; k < 8; ++k) {
            long long c = t + (long long)k * CA_THREADS;   // [0, 2359296)
            int r = (int)(c >> 7);
            cast_chunk_swz(A, Abf, c, r);
        }
    }
}

// ---------- kernel 2: GEMM, asymmetric pipeline ----------
// A (HBM, ~900cyc): double-buffered, counted vmcnt, issued ONE FULL K-STEP
// ahead -> latency covered. B (W matrix: 2MB, L2-resident per XCD, ~200cyc):
// single buffer, staged cold inside the window -- only its short latency is
// exposed. LDS 48 KB -> 3 blocks/CU (R9's symmetric dbuf = 64 KB -> 2).
// ISSUE ORDER LOAD-BEARING: B(k) before A(k+1); FIFO queue at the wait is
// [A(k)4 | B(k)4 | A(k+1)4], so vmcnt(4) retires exactly A(k)+B(k) and
// A(k+1)'s 4 stay in flight across BOTH barriers (T4).
#define BM 128
#define BN 128
#define BK 64
#define KTILES (DD / BK)   // 16

#define VMCNT4()  asm volatile("s_waitcnt vmcnt(4)" ::: "memory")
#define VMCNT0()  asm volatile("s_waitcnt vmcnt(0)" ::: "memory")
#define BAR()     __builtin_amdgcn_s_barrier()

__global__ __launch_bounds__(256, 3) void gemm_kernel(
        const u16* __restrict__ A,    // [MM][DD] bf16, pre-swizzled
        const u16* __restrict__ Bm,   // [NN][DD] bf16, pre-swizzled
        const float* __restrict__ wsT,// [4][MM]
        float* __restrict__ out) {    // [MM][NN] f32
    __shared__ __align__(16) u16 As0[BM * BK];   // 16 KB each
    __shared__ __align__(16) u16 As1[BM * BK];
    __shared__ __align__(16) u16 Bs [BN * BK];

    const int tid = threadIdx.x;
    // XCD-bijective remap: each XCD owns 18 complete row-strips (x 8 col tiles).
    const int bid   = blockIdx.x;       // 0..1151
    const int xcd   = bid & 7;
    const int local = bid >> 3;         // 0..143
    const int by    = xcd * 18 + (local >> 3);
    const int bx    = local & 7;
    const int rowBase = by * BM;
    const int colBase = bx * BN;
    const int lane = tid & 63;
    const int w    = tid >> 6;         // wave 0..3
    const int wr   = w >> 1;           // wave row 0..1 (64-row strip)
    const int wc   = w & 1;            // wave col 0..1 (64-col strip)
    const int fr   = lane & 15;        // fragment row/col
    const int fq   = lane >> 4;        // 0..3

    f32x4 acc[4][4];
#pragma unroll
    for (int m = 0; m < 4; ++m)
#pragma unroll
        for (int n = 0; n < 4; ++n)
            acc[m][n] = (f32x4)0.0f;

    // per-thread staging: chunk (r = tid>>3 + 32*i, j = tid&7), linear source
    const u16* aptr = A  + (size_t)(rowBase + (tid >> 3)) * DD + (tid & 7) * 8;
    const u16* bptr = Bm + (size_t)(colBase + (tid >> 3)) * DD + (tid & 7) * 8;

    auto STAGE_A = [&](u16* as, int kt) {   // 4 vmcnt events
#pragma unroll
        for (int i = 0; i < 4; ++i)
            gld16(aptr + (size_t)i * 32 * DD + kt * BK, &as[(i * 256 + tid) * 8]);
    };
    auto STAGE_B = [&](int kt) {            // 4 vmcnt events
#pragma unroll
        for (int i = 0; i < 4; ++i)
            gld16(bptr + (size_t)i * 32 * DD + kt * BK, &Bs[(i * 256 + tid) * 8]);
    };

    auto COMPUTE = [&](const u16* as) {
#pragma unroll
        for (int kk = 0; kk < 2; ++kk) {
            bf16x8 af[4], bfv[4];
#pragma unroll
            for (int m = 0; m < 4; ++m) {
                int r = wr * 64 + m * 16 + fr;
                int g = kk * 4 + fq;               // bf16x8-chunk index
                af[m] = ((const bf16x8*)&as[r * BK])[g ^ (r & 7)];
            }
#pragma unroll
            for (int n = 0; n < 4; ++n) {
                int r = wc * 64 + n * 16 + fr;
                int g = kk * 4 + fq;
                bfv[n] = ((const bf16x8*)&Bs[r * BK])[g ^ (r & 7)];
            }
#pragma unroll
            for (int m = 0; m < 4; ++m)
#pragma unroll
                for (int n = 0; n < 4; ++n)
                    acc[m][n] = __builtin_amdgcn_mfma_f32_16x16x32_bf16(
                        af[m], bfv[n], acc[m][n], 0, 0, 0);
        }
    };

    // ---- prologue: A(0) issued early (gets the loop-top time as cover) ----
    STAGE_A(As0, 0);

    // ---- steady state: 7 double-iterations; computes tiles 0..13 ----
    // iter k: STAGE_B(k) [cold, ~L2 latency]; STAGE_A(k+1) [full step ahead];
    //         vmcnt(4) [retires A(k)+B(k); A(k+1) flies]; BAR; COMPUTE(k); BAR.
    for (int k2 = 0; k2 < (KTILES - 2) / 2; ++k2) {
        STAGE_B(2 * k2);
        STAGE_A(As1, 2 * k2 + 1);
        VMCNT4();
        BAR();
        COMPUTE(As0);          // tile 2k2
        BAR();                 // WAR: readers done before Bs/As1... overwritten
        STAGE_B(2 * k2 + 1);
        STAGE_A(As0, 2 * k2 + 2);
        VMCNT4();
        BAR();
        COMPUTE(As1);          // tile 2k2+1
        BAR();
    }
    // ---- tail: tiles 14, 15 ----
    STAGE_B(KTILES - 2);
    STAGE_A(As1, KTILES - 1);
    VMCNT4();                  // A(14)+B(14) done; A(15) flies
    BAR();
    COMPUTE(As0);              // tile 14
    BAR();
    STAGE_B(KTILES - 1);
    VMCNT0();                  // A(15)+B(15) done
    BAR();
    COMPUTE(As1);              // tile 15

    // epilogue: out[r][c] = acc * ws[r][kn], kn = bx>>1 (block inside one kernel slab)
    const int kn = bx >> 1;
#pragma unroll
    for (int m = 0; m < 4; ++m) {
        int r0 = rowBase + wr * 64 + m * 16 + fq * 4;
        f32x4 s = *(const f32x4*)&wsT[(size_t)kn * MM + r0];
#pragma unroll
        for (int n = 0; n < 4; ++n) {
            int c = colBase + wc * 64 + n * 16 + fr;
            float* o = out + (size_t)r0 * NN + c;
            o[0 * NN] = acc[m][n][0] * s[0];
            o[1 * NN] = acc[m][n][1] * s[1];
            o[2 * NN] = acc[m][n][2] * s[2];
            o[3 * NN] = acc[m][n][3] * s[3];
        }
    }
}

// ---------- launch ----------
extern "C" void kernel_launch(void* const* d_in, const int* in_sizes, int n_in,
                              void* d_out, int out_size, void* d_ws, size_t ws_size,
                              hipStream_t stream) {
    const float* feat = (const float*)d_in[0];   // [512][36][1024]
    const float* rrw  = (const float*)d_in[1];   // [512][36][36]
    const float* mean = (const float*)d_in[2];   // [4]
    const float* prec = (const float*)d_in[3];   // [4]
    const float* W    = (const float*)d_in[4];   // [4][256][1024] == [1024][1024]
    float* out = (float*)d_out;

    // workspace layout
    char* ws = (char*)d_ws;
    float* wsT = (float*)ws;                          // 294,912 B
    u16*   Wbf = (u16*)(ws + 294912);                 // 2,097,152 B
    u16*   Abf = (u16*)(ws + 294912 + 2097152);       // 37,748,736 B

    prep_kernel<<<dim3(WS_BLOCKS + CW_BLOCKS + CA_BLOCKS), dim3(256), 0, stream>>>(
        rrw, mean, prec, wsT, W, Wbf, feat, Abf);
    gemm_kernel<<<dim3((MM / BM) * (NN / BN)), dim3(256), 0, stream>>>(Abf, Wbf, wsT, out);
}